// Round 4
// baseline (36545.825 us; speedup 1.0000x reference)
//
#include <hip/hip_runtime.h>
#include <hip/hip_bf16.h>
#include <math.h>

#define DD 768
#define FF 3072
#define SS 512
#define BBATCH 16
#define NH 12
#define DH 64
#define NL 4
#define MM (BBATCH*SS)   // 8192

// ---------------- copy kernel ----------------
__global__ __launch_bounds__(256) void copy_f32_k(const float* __restrict__ in,
                                                  float* __restrict__ out, int n) {
  for (int i = blockIdx.x*256 + threadIdx.x; i < n; i += gridDim.x*256)
    out[i] = in[i];
}

// ---------------- GEMM: C[M,N] = A[M,K] @ W[K,N] + bias, epilogue ----
// EPI: 0 = bias only; 1 = bias + residual add; 2 = bias + exact gelu
template<int EPI>
__global__ __launch_bounds__(256) void gemm_k(
    const float* __restrict__ A, const float* __restrict__ W,
    const float* __restrict__ bias, const float* __restrict__ resid,
    float* __restrict__ C, int M, int N, int K)
{
  __shared__ float As[16][65];
  __shared__ float Bs[16][65];
  const int bm = blockIdx.y * 64, bn = blockIdx.x * 64;
  const int tid = threadIdx.x;
  const int tx = tid & 15, ty = tid >> 4;
  float acc[4][4] = {};
  for (int k0 = 0; k0 < K; k0 += 16) {
#pragma unroll
    for (int i = 0; i < 4; ++i) {
      int e = tid + i*256;
      int m  = e >> 4, kk = e & 15;
      As[kk][m] = A[(size_t)(bm+m)*K + (k0+kk)];
      int kk2 = e >> 6, n2 = e & 63;
      Bs[kk2][n2] = W[(size_t)(k0+kk2)*N + (bn+n2)];
    }
    __syncthreads();
#pragma unroll
    for (int kk = 0; kk < 16; ++kk) {
      float a[4], b[4];
#pragma unroll
      for (int i = 0; i < 4; ++i) a[i] = As[kk][ty*4+i];
#pragma unroll
      for (int j = 0; j < 4; ++j) b[j] = Bs[kk][tx*4+j];
#pragma unroll
      for (int i = 0; i < 4; ++i)
#pragma unroll
        for (int j = 0; j < 4; ++j)
          acc[i][j] = fmaf(a[i], b[j], acc[i][j]);
    }
    __syncthreads();
  }
#pragma unroll
  for (int i = 0; i < 4; ++i) {
    int r = bm + ty*4 + i;
#pragma unroll
    for (int j = 0; j < 4; ++j) {
      int cidx = bn + tx*4 + j;
      float v = acc[i][j] + bias[cidx];
      if (EPI == 1) v += resid[(size_t)r*N + cidx];
      if (EPI == 2) v = 0.5f*v*(1.0f + erff(v*0.70710678118654752f));
      C[(size_t)r*N + cidx] = v;
    }
  }
}

// ---------------- per-(b,h,s) context-vector L2 norm ----------------
// cn layout: [B, H, S] -> cn[(b*NH + h)*SS + s]
__global__ __launch_bounds__(64) void cnorm_k(const float* __restrict__ c,
                                              float* __restrict__ cn) {
  int idx = blockIdx.x;          // (b*NH + h)*SS + s
  int s  = idx % SS;
  int bh = idx / SS;
  int h  = bh % NH;
  int b  = bh / NH;
  int tid = threadIdx.x;
  float v = c[((size_t)(b*SS + s))*DD + h*DH + tid];
  float ss = v*v;
#pragma unroll
  for (int off = 32; off; off >>= 1) ss += __shfl_xor(ss, off, 64);
  if (tid == 0) cn[idx] = sqrtf(ss);
}

// ---------------- attention: one wave per (b,h,query-row) ----------------
__global__ __launch_bounds__(64) void attn_k(
    const float* __restrict__ q, const float* __restrict__ k,
    const float* __restrict__ v, const float* __restrict__ c,
    const float* __restrict__ cn, float* __restrict__ ctx)
{
  const float scale = 0.125f;            // 1/sqrt(64)
  int idx = blockIdx.x;                  // (b*NH + h)*SS + l
  int l  = idx % SS;
  int bh = idx / SS;
  int h  = bh % NH;
  int b  = bh / NH;
  int tid = threadIdx.x;
  size_t rowbase = ((size_t)(b*SS))*DD + h*DH;   // + r*DD + d

  __shared__ float ql[DH], cl[DH], p[SS];
  ql[tid] = q[rowbase + (size_t)l*DD + tid];
  cl[tid] = c[rowbase + (size_t)l*DD + tid];
  __syncthreads();
  float cn_l = cn[bh*SS + l];

  float s1v[8], s2v[8];
#pragma unroll
  for (int j = 0; j < 8; ++j) {
    int r = j*64 + tid;
    const float4* kr = (const float4*)(k + rowbase + (size_t)r*DD);
    const float4* cr = (const float4*)(c + rowbase + (size_t)r*DD);
    float qk = 0.f, cc = 0.f;
#pragma unroll
    for (int d4 = 0; d4 < 16; ++d4) {
      float4 k4 = kr[d4], c4 = cr[d4];
      qk = fmaf(ql[d4*4+0], k4.x, qk); qk = fmaf(ql[d4*4+1], k4.y, qk);
      qk = fmaf(ql[d4*4+2], k4.z, qk); qk = fmaf(ql[d4*4+3], k4.w, qk);
      cc = fmaf(cl[d4*4+0], c4.x, cc); cc = fmaf(cl[d4*4+1], c4.y, cc);
      cc = fmaf(cl[d4*4+2], c4.z, cc); cc = fmaf(cl[d4*4+3], c4.w, cc);
    }
    float denom = cn_l * cn[bh*SS + r];
    s1v[j] = 1.0f - cc/denom + (r == l ? 1.0f : 0.0f);
    s2v[j] = qk * scale;
  }
  // softmax over both branches (512 scores each)
  float m1 = -1e30f, m2 = -1e30f;
#pragma unroll
  for (int j = 0; j < 8; ++j) { m1 = fmaxf(m1, s1v[j]); m2 = fmaxf(m2, s2v[j]); }
#pragma unroll
  for (int off = 32; off; off >>= 1) {
    m1 = fmaxf(m1, __shfl_xor(m1, off, 64));
    m2 = fmaxf(m2, __shfl_xor(m2, off, 64));
  }
  float sum1 = 0.f, sum2 = 0.f;
#pragma unroll
  for (int j = 0; j < 8; ++j) {
    s1v[j] = expf(s1v[j] - m1); sum1 += s1v[j];
    s2v[j] = expf(s2v[j] - m2); sum2 += s2v[j];
  }
#pragma unroll
  for (int off = 32; off; off >>= 1) {
    sum1 += __shfl_xor(sum1, off, 64);
    sum2 += __shfl_xor(sum2, off, 64);
  }
  float inv1 = 0.5f/sum1, inv2 = 0.5f/sum2;
#pragma unroll
  for (int j = 0; j < 8; ++j)
    p[j*64 + tid] = s1v[j]*inv1 + s2v[j]*inv2;
  __syncthreads();

  // ctx[l][d] = sum_r p[r] * v[r][d]; lane = d, coalesced v reads
  float acc = 0.f;
  for (int r = 0; r < SS; ++r)
    acc = fmaf(p[r], v[rowbase + (size_t)r*DD + tid], acc);
  ctx[rowbase + (size_t)l*DD + tid] = acc;
}

// ---------------- in-place row LayerNorm over D=768 ----------------
__global__ __launch_bounds__(256) void ln_k(float* __restrict__ x,
                                            const float* __restrict__ g,
                                            const float* __restrict__ b) {
  __shared__ float xs[DD];
  __shared__ float red[4];
  const int tid = threadIdx.x;
  float* xr = x + (size_t)blockIdx.x * DD;
  float s = 0.f;
  for (int d = tid; d < DD; d += 256) { float v = xr[d]; xs[d] = v; s += v; }
#pragma unroll
  for (int off = 32; off; off >>= 1) s += __shfl_xor(s, off, 64);
  if ((tid & 63) == 0) red[tid >> 6] = s;
  __syncthreads();
  float mu = (red[0]+red[1]+red[2]+red[3]) * (1.f/DD);
  __syncthreads();
  float s2 = 0.f;
  for (int d = tid; d < DD; d += 256) { float t = xs[d]-mu; s2 += t*t; }
#pragma unroll
  for (int off = 32; off; off >>= 1) s2 += __shfl_xor(s2, off, 64);
  if ((tid & 63) == 0) red[tid >> 6] = s2;
  __syncthreads();
  float var = (red[0]+red[1]+red[2]+red[3]) * (1.f/DD);
  float rstd = rsqrtf(var + 1e-12f);
  for (int d = tid; d < DD; d += 256)
    xr[d] = (xs[d]-mu)*rstd*g[d] + b[d];
}

// ---------------- launcher ----------------
extern "C" void kernel_launch(void* const* d_in, const int* in_sizes, int n_in,
                              void* d_out, int out_size, void* d_ws, size_t ws_size,
                              hipStream_t stream) {
  const float* hs  = (const float*)d_in[0];
  const float* Wq  = (const float*)d_in[1];  const float* bq  = (const float*)d_in[2];
  const float* Wk  = (const float*)d_in[3];  const float* bk  = (const float*)d_in[4];
  const float* Wv  = (const float*)d_in[5];  const float* bv  = (const float*)d_in[6];
  const float* Wc  = (const float*)d_in[7];  const float* bc  = (const float*)d_in[8];
  const float* Wo  = (const float*)d_in[9];  const float* bo  = (const float*)d_in[10];
  const float* g1  = (const float*)d_in[11]; const float* b1  = (const float*)d_in[12];
  const float* Wi  = (const float*)d_in[13]; const float* bi  = (const float*)d_in[14];
  const float* Wo2 = (const float*)d_in[15]; const float* bo2 = (const float*)d_in[16];
  const float* g2  = (const float*)d_in[17]; const float* b2  = (const float*)d_in[18];

  const size_t XN = (size_t)MM * DD;          // 6,291,456 floats
  float* ws   = (float*)d_ws;
  float* x    = ws;                            // [MM,DD]
  float* qb   = ws + 1*XN;                     // q / also start of h buffer
  float* kb   = ws + 2*XN;
  float* vb   = ws + 3*XN;
  float* cb   = ws + 4*XN;
  float* hb   = qb;                            // [MM,FF] == 4*XN floats (q..c dead)
  float* ctx  = ws + 5*XN;
  float* attn = ws + 6*XN;
  float* cnb  = ws + 7*XN;                     // [B*NH*SS]
  const size_t need = (7*XN + (size_t)BBATCH*NH*SS) * sizeof(float);
  if (ws_size < need) return;                  // workspace too small: bail

  copy_f32_k<<<4096, 256, 0, stream>>>(hs, x, (int)XN);

  dim3 gD(DD/64, MM/64);   // 12 x 128
  dim3 gF(FF/64, MM/64);   // 48 x 128
  const int nBH = BBATCH*NH*SS;               // 98304

  for (int i = 0; i < NL; ++i) {
    const size_t wo = (size_t)i*DD*DD;
    gemm_k<0><<<gD, 256, 0, stream>>>(x, Wq + wo, bq + (size_t)i*DD, nullptr, qb, MM, DD, DD);
    gemm_k<0><<<gD, 256, 0, stream>>>(x, Wk + wo, bk + (size_t)i*DD, nullptr, kb, MM, DD, DD);
    gemm_k<0><<<gD, 256, 0, stream>>>(x, Wv + wo, bv + (size_t)i*DD, nullptr, vb, MM, DD, DD);
    gemm_k<0><<<gD, 256, 0, stream>>>(x, Wc + wo, bc + (size_t)i*DD, nullptr, cb, MM, DD, DD);

    cnorm_k<<<nBH, 64, 0, stream>>>(cb, cnb);
    attn_k<<<nBH, 64, 0, stream>>>(qb, kb, vb, cb, cnb, ctx);

    gemm_k<1><<<gD, 256, 0, stream>>>(ctx, Wo + wo, bo + (size_t)i*DD, x, attn, MM, DD, DD);
    ln_k<<<MM, 256, 0, stream>>>(attn, g1 + (size_t)i*DD, b1 + (size_t)i*DD);

    gemm_k<2><<<gF, 256, 0, stream>>>(attn, Wi + (size_t)i*DD*FF, bi + (size_t)i*FF, nullptr, hb, MM, FF, DD);
    gemm_k<1><<<gD, 256, 0, stream>>>(hb, Wo2 + (size_t)i*FF*DD, bo2 + (size_t)i*DD, attn, x, MM, DD, FF);
    ln_k<<<MM, 256, 0, stream>>>(x, g2 + (size_t)i*DD, b2 + (size_t)i*DD);
  }

  // Reference output dtype is float32 — store fp32, NOT bf16.
  copy_f32_k<<<4096, 256, 0, stream>>>(x, (float*)d_out, (int)XN);
}

// Round 5
// 24004.776 us; speedup vs baseline: 1.5224x; 1.5224x over previous
//
#include <hip/hip_runtime.h>
#include <hip/hip_bf16.h>
#include <math.h>

#define DD 768
#define FF 3072
#define SS 512
#define BBATCH 16
#define NH 12
#define DH 64
#define NL 4
#define MM (BBATCH*SS)   // 8192

// ---------------- copy kernel ----------------
__global__ __launch_bounds__(256) void copy_f32_k(const float* __restrict__ in,
                                                  float* __restrict__ out, int n) {
  for (int i = blockIdx.x*256 + threadIdx.x; i < n; i += gridDim.x*256)
    out[i] = in[i];
}

// ---------------- GEMM: C[M,N] = A[M,K] @ W[K,N] + bias, epilogue ----
// EPI: 0 = bias only; 1 = bias + residual add; 2 = bias + exact gelu
template<int EPI>
__global__ __launch_bounds__(256) void gemm_k(
    const float* __restrict__ A, const float* __restrict__ W,
    const float* __restrict__ bias, const float* __restrict__ resid,
    float* __restrict__ C, int M, int N, int K)
{
  __shared__ float As[16][65];
  __shared__ float Bs[16][65];
  const int bm = blockIdx.y * 64, bn = blockIdx.x * 64;
  const int tid = threadIdx.x;
  const int tx = tid & 15, ty = tid >> 4;
  float acc[4][4] = {};
  for (int k0 = 0; k0 < K; k0 += 16) {
#pragma unroll
    for (int i = 0; i < 4; ++i) {
      int e = tid + i*256;
      int m  = e >> 4, kk = e & 15;
      As[kk][m] = A[(size_t)(bm+m)*K + (k0+kk)];
      int kk2 = e >> 6, n2 = e & 63;
      Bs[kk2][n2] = W[(size_t)(k0+kk2)*N + (bn+n2)];
    }
    __syncthreads();
#pragma unroll
    for (int kk = 0; kk < 16; ++kk) {
      float a[4], b[4];
#pragma unroll
      for (int i = 0; i < 4; ++i) a[i] = As[kk][ty*4+i];
#pragma unroll
      for (int j = 0; j < 4; ++j) b[j] = Bs[kk][tx*4+j];
#pragma unroll
      for (int i = 0; i < 4; ++i)
#pragma unroll
        for (int j = 0; j < 4; ++j)
          acc[i][j] = fmaf(a[i], b[j], acc[i][j]);
    }
    __syncthreads();
  }
#pragma unroll
  for (int i = 0; i < 4; ++i) {
    int r = bm + ty*4 + i;
#pragma unroll
    for (int j = 0; j < 4; ++j) {
      int cidx = bn + tx*4 + j;
      float v = acc[i][j] + bias[cidx];
      if (EPI == 1) v += resid[(size_t)r*N + cidx];
      if (EPI == 2) v = 0.5f*v*(1.0f + erff(v*0.70710678118654752f));
      C[(size_t)r*N + cidx] = v;
    }
  }
}

// ---------------- per-(b,h,s) context-vector L2 norm ----------------
__global__ __launch_bounds__(64) void cnorm_k(const float* __restrict__ c,
                                              float* __restrict__ cn) {
  int idx = blockIdx.x;          // (b*NH + h)*SS + s
  int s  = idx % SS;
  int bh = idx / SS;
  int h  = bh % NH;
  int b  = bh / NH;
  int tid = threadIdx.x;
  float v = c[((size_t)(b*SS + s))*DD + h*DH + tid];
  float ss = v*v;
#pragma unroll
  for (int off = 32; off; off >>= 1) ss += __shfl_xor(ss, off, 64);
  if (tid == 0) cn[idx] = sqrtf(ss);
}

// ---------------- fused flash-style dual-branch attention ----------------
// Block: (qtile of 32 rows, head h, batch b), 256 threads (4 waves).
// Streams 8 key-tiles of 64; online softmax for both branches; V staged
// into the dead C buffer after scores. LDS ~71.8 KB -> 2 blocks/CU.
__global__ __launch_bounds__(256) void attn2_k(
    const float* __restrict__ q, const float* __restrict__ k,
    const float* __restrict__ v, const float* __restrict__ c,
    const float* __restrict__ cn, float* __restrict__ ctx)
{
  const int l0 = blockIdx.x * 32;
  const int h  = blockIdx.y;
  const int b  = blockIdx.z;
  const int tid = threadIdx.x;
  const int bh = b*NH + h;
  const size_t base = (size_t)(b*SS)*DD + h*DH;   // + row*DD + d

  __shared__ float Qs [32][68];
  __shared__ float Cls[32][68];
  __shared__ float Ks [64][68];
  __shared__ float Cs [64][68];   // holds C-tile for scores, then V-tile for PV
  __shared__ float P1 [32][68];
  __shared__ float P2 [32][68];
  __shared__ float cnl[32], cnr[64];
  __shared__ float m1s[32], s1s[32], sc1[32];
  __shared__ float m2s[32], s2s[32], sc2[32];

  // stage Q and C_l tiles (32 rows x 64)
  {
    int row = tid >> 3, j0 = tid & 7;
    const float* qg = q + base + (size_t)(l0+row)*DD;
    const float* cg = c + base + (size_t)(l0+row)*DD;
    *(float4*)&Qs [row][j0*4]     = *(const float4*)&qg[j0*4];
    *(float4*)&Qs [row][(j0+8)*4] = *(const float4*)&qg[(j0+8)*4];
    *(float4*)&Cls[row][j0*4]     = *(const float4*)&cg[j0*4];
    *(float4*)&Cls[row][(j0+8)*4] = *(const float4*)&cg[(j0+8)*4];
  }
  if (tid < 32) {
    cnl[tid] = cn[(size_t)bh*SS + l0 + tid];
    m1s[tid] = -1e30f; s1s[tid] = 0.f;
    m2s[tid] = -1e30f; s2s[tid] = 0.f;
  }
  __syncthreads();

  const int ty = tid >> 4, tx = tid & 15;   // score mapping: l=ty*2+i, r=tx+16j
  const int lpv = tid >> 3, dq = tid & 7;   // PV mapping: (l, d-octet)
  float ctx1[8] = {0,0,0,0,0,0,0,0};
  float ctx2[8] = {0,0,0,0,0,0,0,0};

  for (int it = 0; it < 8; ++it) {
    const int r0 = it*64;
    // ---- stage K and C key-tiles ----
    {
      int row = tid >> 2, cix = tid & 3;
      const float* kg = k + base + (size_t)(r0+row)*DD;
      const float* cg = c + base + (size_t)(r0+row)*DD;
#pragma unroll
      for (int jj = 0; jj < 4; ++jj) {
        *(float4*)&Ks[row][(jj*4+cix)*4] = *(const float4*)&kg[(jj*4+cix)*4];
        *(float4*)&Cs[row][(jj*4+cix)*4] = *(const float4*)&cg[(jj*4+cix)*4];
      }
      if (tid < 64) cnr[tid] = cn[(size_t)bh*SS + r0 + tid];
    }
    __syncthreads();

    // ---- dual scores, register tile 2l x 4r ----
    float qk[2][4] = {}, cc[2][4] = {};
#pragma unroll
    for (int d4 = 0; d4 < 16; ++d4) {
      const float4 q0 = *(const float4*)&Qs [ty*2  ][d4*4];
      const float4 q1 = *(const float4*)&Qs [ty*2+1][d4*4];
      const float4 a0 = *(const float4*)&Cls[ty*2  ][d4*4];
      const float4 a1 = *(const float4*)&Cls[ty*2+1][d4*4];
#pragma unroll
      for (int j = 0; j < 4; ++j) {
        const float4 k4 = *(const float4*)&Ks[tx + 16*j][d4*4];
        const float4 c4 = *(const float4*)&Cs[tx + 16*j][d4*4];
        qk[0][j] = fmaf(q0.x,k4.x, fmaf(q0.y,k4.y, fmaf(q0.z,k4.z, fmaf(q0.w,k4.w, qk[0][j]))));
        qk[1][j] = fmaf(q1.x,k4.x, fmaf(q1.y,k4.y, fmaf(q1.z,k4.z, fmaf(q1.w,k4.w, qk[1][j]))));
        cc[0][j] = fmaf(a0.x,c4.x, fmaf(a0.y,c4.y, fmaf(a0.z,c4.z, fmaf(a0.w,c4.w, cc[0][j]))));
        cc[1][j] = fmaf(a1.x,c4.x, fmaf(a1.y,c4.y, fmaf(a1.z,c4.z, fmaf(a1.w,c4.w, cc[1][j]))));
      }
    }

    // ---- online-softmax stats + exp tiles ----
#pragma unroll
    for (int i = 0; i < 2; ++i) {
      const int l  = ty*2 + i;
      const int lg = l0 + l;
      const float cni = cnl[l];
      float s1[4], s2[4];
#pragma unroll
      for (int j = 0; j < 4; ++j) {
        const int rl = tx + 16*j;
        s2[j] = qk[i][j] * 0.125f;
        s1[j] = 1.0f - cc[i][j]/(cni*cnr[rl]) + ((lg == r0+rl) ? 1.0f : 0.0f);
      }
      float t1 = fmaxf(fmaxf(s1[0],s1[1]), fmaxf(s1[2],s1[3]));
      float t2 = fmaxf(fmaxf(s2[0],s2[1]), fmaxf(s2[2],s2[3]));
#pragma unroll
      for (int off = 1; off < 16; off <<= 1) {
        t1 = fmaxf(t1, __shfl_xor(t1, off, 64));
        t2 = fmaxf(t2, __shfl_xor(t2, off, 64));
      }
      const float mo1 = m1s[l], mo2 = m2s[l];
      const float mn1 = fmaxf(mo1, t1), mn2 = fmaxf(mo2, t2);
      float e1sum = 0.f, e2sum = 0.f;
#pragma unroll
      for (int j = 0; j < 4; ++j) {
        const float e1 = __expf(s1[j] - mn1);
        const float e2 = __expf(s2[j] - mn2);
        P1[l][tx + 16*j] = e1;  e1sum += e1;
        P2[l][tx + 16*j] = e2;  e2sum += e2;
      }
#pragma unroll
      for (int off = 1; off < 16; off <<= 1) {
        e1sum += __shfl_xor(e1sum, off, 64);
        e2sum += __shfl_xor(e2sum, off, 64);
      }
      if (tx == 0) {
        const float f1 = __expf(mo1 - mn1);
        const float f2 = __expf(mo2 - mn2);
        s1s[l] = s1s[l]*f1 + e1sum;  m1s[l] = mn1;  sc1[l] = f1;
        s2s[l] = s2s[l]*f2 + e2sum;  m2s[l] = mn2;  sc2[l] = f2;
      }
    }
    __syncthreads();   // P1/P2, sc*, stats visible; scores done with Cs

    // ---- stage V tile into Cs ----
    {
      int row = tid >> 2, cix = tid & 3;
      const float* vg = v + base + (size_t)(r0+row)*DD;
#pragma unroll
      for (int jj = 0; jj < 4; ++jj)
        *(float4*)&Cs[row][(jj*4+cix)*4] = *(const float4*)&vg[(jj*4+cix)*4];
    }
    __syncthreads();

    // ---- PV accumulate with rescale ----
    {
      const float f1 = sc1[lpv], f2 = sc2[lpv];
#pragma unroll
      for (int z = 0; z < 8; ++z) { ctx1[z] *= f1; ctx2[z] *= f2; }
      for (int r4 = 0; r4 < 64; r4 += 4) {
        const float4 p1v = *(const float4*)&P1[lpv][r4];
        const float4 p2v = *(const float4*)&P2[lpv][r4];
#pragma unroll
        for (int rr = 0; rr < 4; ++rr) {
          const float w1 = ((const float*)&p1v)[rr];
          const float w2 = ((const float*)&p2v)[rr];
          const float4 va = *(const float4*)&Cs[r4+rr][dq*8];
          const float4 vb = *(const float4*)&Cs[r4+rr][dq*8+4];
          ctx1[0]=fmaf(w1,va.x,ctx1[0]); ctx1[1]=fmaf(w1,va.y,ctx1[1]);
          ctx1[2]=fmaf(w1,va.z,ctx1[2]); ctx1[3]=fmaf(w1,va.w,ctx1[3]);
          ctx1[4]=fmaf(w1,vb.x,ctx1[4]); ctx1[5]=fmaf(w1,vb.y,ctx1[5]);
          ctx1[6]=fmaf(w1,vb.z,ctx1[6]); ctx1[7]=fmaf(w1,vb.w,ctx1[7]);
          ctx2[0]=fmaf(w2,va.x,ctx2[0]); ctx2[1]=fmaf(w2,va.y,ctx2[1]);
          ctx2[2]=fmaf(w2,va.z,ctx2[2]); ctx2[3]=fmaf(w2,va.w,ctx2[3]);
          ctx2[4]=fmaf(w2,vb.x,ctx2[4]); ctx2[5]=fmaf(w2,vb.y,ctx2[5]);
          ctx2[6]=fmaf(w2,vb.z,ctx2[6]); ctx2[7]=fmaf(w2,vb.w,ctx2[7]);
        }
      }
    }
    __syncthreads();   // PV done before next tile overwrites Ks/Cs/P
  }

  // ---- final blend + store ----
  const float inv1 = 0.5f / s1s[lpv];
  const float inv2 = 0.5f / s2s[lpv];
  float* og = ctx + base + (size_t)(l0+lpv)*DD + dq*8;
  float4 o0, o1;
  o0.x = ctx1[0]*inv1 + ctx2[0]*inv2;  o0.y = ctx1[1]*inv1 + ctx2[1]*inv2;
  o0.z = ctx1[2]*inv1 + ctx2[2]*inv2;  o0.w = ctx1[3]*inv1 + ctx2[3]*inv2;
  o1.x = ctx1[4]*inv1 + ctx2[4]*inv2;  o1.y = ctx1[5]*inv1 + ctx2[5]*inv2;
  o1.z = ctx1[6]*inv1 + ctx2[6]*inv2;  o1.w = ctx1[7]*inv1 + ctx2[7]*inv2;
  *(float4*)&og[0] = o0;
  *(float4*)&og[4] = o1;
}

// ---------------- in-place row LayerNorm over D=768 ----------------
__global__ __launch_bounds__(256) void ln_k(float* __restrict__ x,
                                            const float* __restrict__ g,
                                            const float* __restrict__ b) {
  __shared__ float xs[DD];
  __shared__ float red[4];
  const int tid = threadIdx.x;
  float* xr = x + (size_t)blockIdx.x * DD;
  float s = 0.f;
  for (int d = tid; d < DD; d += 256) { float v = xr[d]; xs[d] = v; s += v; }
#pragma unroll
  for (int off = 32; off; off >>= 1) s += __shfl_xor(s, off, 64);
  if ((tid & 63) == 0) red[tid >> 6] = s;
  __syncthreads();
  float mu = (red[0]+red[1]+red[2]+red[3]) * (1.f/DD);
  __syncthreads();
  float s2 = 0.f;
  for (int d = tid; d < DD; d += 256) { float t = xs[d]-mu; s2 += t*t; }
#pragma unroll
  for (int off = 32; off; off >>= 1) s2 += __shfl_xor(s2, off, 64);
  if ((tid & 63) == 0) red[tid >> 6] = s2;
  __syncthreads();
  float var = (red[0]+red[1]+red[2]+red[3]) * (1.f/DD);
  float rstd = rsqrtf(var + 1e-12f);
  for (int d = tid; d < DD; d += 256)
    xr[d] = (xs[d]-mu)*rstd*g[d] + b[d];
}

// ---------------- launcher ----------------
extern "C" void kernel_launch(void* const* d_in, const int* in_sizes, int n_in,
                              void* d_out, int out_size, void* d_ws, size_t ws_size,
                              hipStream_t stream) {
  const float* hs  = (const float*)d_in[0];
  const float* Wq  = (const float*)d_in[1];  const float* bq  = (const float*)d_in[2];
  const float* Wk  = (const float*)d_in[3];  const float* bk  = (const float*)d_in[4];
  const float* Wv  = (const float*)d_in[5];  const float* bv  = (const float*)d_in[6];
  const float* Wc  = (const float*)d_in[7];  const float* bc  = (const float*)d_in[8];
  const float* Wo  = (const float*)d_in[9];  const float* bo  = (const float*)d_in[10];
  const float* g1  = (const float*)d_in[11]; const float* b1  = (const float*)d_in[12];
  const float* Wi  = (const float*)d_in[13]; const float* bi  = (const float*)d_in[14];
  const float* Wo2 = (const float*)d_in[15]; const float* bo2 = (const float*)d_in[16];
  const float* g2  = (const float*)d_in[17]; const float* b2  = (const float*)d_in[18];

  const size_t XN = (size_t)MM * DD;          // 6,291,456 floats
  float* ws   = (float*)d_ws;
  float* x    = ws;                            // [MM,DD]
  float* qb   = ws + 1*XN;                     // q / also start of h buffer
  float* kb   = ws + 2*XN;
  float* vb   = ws + 3*XN;
  float* cb   = ws + 4*XN;
  float* hb   = qb;                            // [MM,FF] == 4*XN floats (q..c dead)
  float* ctx  = ws + 5*XN;
  float* attn = ws + 6*XN;
  float* cnb  = ws + 7*XN;                     // [B*NH*SS]
  const size_t need = (7*XN + (size_t)BBATCH*NH*SS) * sizeof(float);
  if (ws_size < need) return;                  // workspace too small: bail

  copy_f32_k<<<4096, 256, 0, stream>>>(hs, x, (int)XN);

  dim3 gD(DD/64, MM/64);   // 12 x 128
  dim3 gF(FF/64, MM/64);   // 48 x 128
  dim3 gA(SS/32, NH, BBATCH);                 // 16 x 12 x 16 = 3072
  const int nBH = BBATCH*NH*SS;               // 98304

  for (int i = 0; i < NL; ++i) {
    const size_t wo = (size_t)i*DD*DD;
    gemm_k<0><<<gD, 256, 0, stream>>>(x, Wq + wo, bq + (size_t)i*DD, nullptr, qb, MM, DD, DD);
    gemm_k<0><<<gD, 256, 0, stream>>>(x, Wk + wo, bk + (size_t)i*DD, nullptr, kb, MM, DD, DD);
    gemm_k<0><<<gD, 256, 0, stream>>>(x, Wv + wo, bv + (size_t)i*DD, nullptr, vb, MM, DD, DD);
    gemm_k<0><<<gD, 256, 0, stream>>>(x, Wc + wo, bc + (size_t)i*DD, nullptr, cb, MM, DD, DD);

    cnorm_k<<<nBH, 64, 0, stream>>>(cb, cnb);
    attn2_k<<<gA, 256, 0, stream>>>(qb, kb, vb, cb, cnb, ctx);

    gemm_k<1><<<gD, 256, 0, stream>>>(ctx, Wo + wo, bo + (size_t)i*DD, x, attn, MM, DD, DD);
    ln_k<<<MM, 256, 0, stream>>>(attn, g1 + (size_t)i*DD, b1 + (size_t)i*DD);

    gemm_k<2><<<gF, 256, 0, stream>>>(attn, Wi + (size_t)i*DD*FF, bi + (size_t)i*FF, nullptr, hb, MM, FF, DD);
    gemm_k<1><<<gD, 256, 0, stream>>>(hb, Wo2 + (size_t)i*FF*DD, bo2 + (size_t)i*DD, attn, x, MM, DD, FF);
    ln_k<<<MM, 256, 0, stream>>>(x, g2 + (size_t)i*DD, b2 + (size_t)i*DD);
  }

  // Reference output dtype is float32 — store fp32, NOT bf16.
  copy_f32_k<<<4096, 256, 0, stream>>>(x, (float*)d_out, (int)XN);
}

// Round 6
// 13536.060 us; speedup vs baseline: 2.6999x; 1.7734x over previous
//
#include <hip/hip_runtime.h>
#include <math.h>

#define DD 768
#define FF 3072
#define SS 512
#define BB 16
#define NH 12
#define DH 64
#define NL 4
#define MM (BB*SS)   // 8192

typedef __attribute__((ext_vector_type(8))) short short8;
typedef __attribute__((ext_vector_type(4))) float f32x4;

__device__ __forceinline__ unsigned short f2bf(float f) {
  unsigned u = __float_as_uint(f);
  return (unsigned short)((u + 0x7FFFu + ((u >> 16) & 1u)) >> 16);
}
__device__ __forceinline__ float bf2f(unsigned short s) {
  return __uint_as_float(((unsigned)s) << 16);
}

#define GLOAD_LDS(g, l) \
  __builtin_amdgcn_global_load_lds((const __attribute__((address_space(1))) void*)(g), \
                                   (__attribute__((address_space(3))) void*)(l), 16, 0, 0)

// ---------------- copy / convert ----------------
__global__ __launch_bounds__(256) void copy_f32_k(const float* __restrict__ in,
                                                  float* __restrict__ out, int n) {
  for (int i = blockIdx.x*256 + threadIdx.x; i < n; i += gridDim.x*256)
    out[i] = in[i];
}
__global__ __launch_bounds__(256) void cvt_dual_k(const float* __restrict__ in,
                                                  float* __restrict__ outf,
                                                  unsigned short* __restrict__ outb, int n) {
  for (int i = blockIdx.x*256 + threadIdx.x; i < n; i += gridDim.x*256) {
    float v = in[i]; outf[i] = v; outb[i] = f2bf(v);
  }
}

// fp32 [K,N] -> bf16 [N,K] tiled transpose-convert
__global__ __launch_bounds__(256) void tcvt_k(const float* __restrict__ src,
                                              unsigned short* __restrict__ dst,
                                              int K, int N) {
  __shared__ float t[32][33];
  const int n0 = blockIdx.x*32, k0 = blockIdx.y*32;
  const int tx = threadIdx.x & 31, ty = threadIdx.x >> 5;
#pragma unroll
  for (int i = 0; i < 32; i += 8)
    t[ty+i][tx] = src[(size_t)(k0+ty+i)*N + n0+tx];
  __syncthreads();
#pragma unroll
  for (int i = 0; i < 32; i += 8)
    dst[(size_t)(n0+ty+i)*K + k0+tx] = f2bf(t[tx][ty+i]);
}

// concat 4x768 biases -> 3072
__global__ __launch_bounds__(256) void bcat_k(const float* __restrict__ a,
                                              const float* __restrict__ b,
                                              const float* __restrict__ c,
                                              const float* __restrict__ d,
                                              float* __restrict__ out) {
  int i = blockIdx.x*256 + threadIdx.x;   // 0..3071
  int w = i / 768;
  const float* s = (w == 0) ? a : (w == 1) ? b : (w == 2) ? c : d;
  out[i] = s[i - w*768];
}

// ---------------- MFMA bf16 GEMM: C[M,N] = A[M,K] @ Bw[N,K]^T + bias ----------------
// EPI: 0 bias; 1 bias+resid(fp32); 2 bias+exact gelu.  OBF: 1 -> bf16 out, 0 -> fp32 out.
template<int EPI, int OBF>
__global__ __launch_bounds__(256) void mgemm_k(
    const unsigned short* __restrict__ A,   // [M,K] bf16
    const unsigned short* __restrict__ Bw,  // [N,K] bf16 (pre-transposed weights)
    const float* __restrict__ bias,         // [N] fp32
    const float* __restrict__ resid,        // [M,N] fp32 (EPI==1)
    void* __restrict__ Cout, int M, int N, int K)
{
  __shared__ __align__(16) unsigned short As[128*32];
  __shared__ __align__(16) unsigned short Bs[128*32];
  const int bm = blockIdx.y*128, bn = blockIdx.x*128;
  const int tid = threadIdx.x;
  const int wave = tid >> 6, lane = tid & 63;
  const int wm = (wave >> 1)*64, wn = (wave & 1)*64;

  f32x4 acc[4][4] = {};

  // wave stages rows [wave*32, wave*32+32) of both tiles; lane -> (row=lane>>2, 16B seg=lane&3)
  const unsigned short* Ag = A  + (size_t)(bm + wave*32 + (lane>>2))*K + (lane&3)*8;
  const unsigned short* Bg = Bw + (size_t)(bn + wave*32 + (lane>>2))*K + (lane&3)*8;
  unsigned short* AsW = As + wave*32*32;
  unsigned short* BsW = Bs + wave*32*32;

  for (int k0 = 0; k0 < K; k0 += 32) {
    GLOAD_LDS(Ag,              AsW);
    GLOAD_LDS(Ag + 16*(size_t)K, AsW + 16*32);
    GLOAD_LDS(Bg,              BsW);
    GLOAD_LDS(Bg + 16*(size_t)K, BsW + 16*32);
    Ag += 32; Bg += 32;
    __syncthreads();                      // drains vmcnt -> LDS tiles ready
    short8 af[4], bfr[4];
#pragma unroll
    for (int i = 0; i < 4; ++i) {
      af[i]  = *(const short8*)&As[(wm + i*16 + (lane & 15))*32 + (lane >> 4)*8];
      bfr[i] = *(const short8*)&Bs[(wn + i*16 + (lane & 15))*32 + (lane >> 4)*8];
    }
#pragma unroll
    for (int i = 0; i < 4; ++i)
#pragma unroll
      for (int j = 0; j < 4; ++j)
        acc[i][j] = __builtin_amdgcn_mfma_f32_16x16x32_bf16(af[i], bfr[j], acc[i][j], 0, 0, 0);
    __syncthreads();                      // compute done before next overwrite
  }

  const int col0 = bn + wn + (lane & 15);
  const int row0 = bm + wm + (lane >> 4)*4;
#pragma unroll
  for (int i = 0; i < 4; ++i) {
#pragma unroll
    for (int j = 0; j < 4; ++j) {
      const int n = col0 + j*16;
      const float bv = bias[n];
#pragma unroll
      for (int r = 0; r < 4; ++r) {
        const int m = row0 + i*16 + r;
        float v = acc[i][j][r] + bv;
        if (EPI == 1) v += resid[(size_t)m*N + n];
        if (EPI == 2) v = 0.5f*v*(1.0f + erff(v*0.70710678118654752f));
        if (OBF) ((unsigned short*)Cout)[(size_t)m*N + n] = f2bf(v);
        else     ((float*)Cout)[(size_t)m*N + n] = v;
      }
    }
  }
}

// ---------------- per-(b,h,s) context-vector L2 norm (bf16 in, pitch FF) ----------------
__global__ __launch_bounds__(64) void cnorm_k(const unsigned short* __restrict__ c,
                                              float* __restrict__ cn) {
  int idx = blockIdx.x;          // (b*NH + h)*SS + s
  int s  = idx % SS;
  int bh = idx / SS;
  int h  = bh % NH;
  int b  = bh / NH;
  int tid = threadIdx.x;
  float v = bf2f(c[((size_t)(b*SS + s))*FF + h*DH + tid]);
  float ss = v*v;
#pragma unroll
  for (int off = 32; off; off >>= 1) ss += __shfl_xor(ss, off, 64);
  if (tid == 0) cn[idx] = sqrtf(ss);
}

// ---------------- fused flash-style dual-branch attention (bf16 in/out) ----------------
// q/k/v/c: bf16 slices of [MM,FF] fused QKVC buffer (pitch FF). ctx out: bf16 [MM,DD].
__global__ __launch_bounds__(256) void attn2_k(
    const unsigned short* __restrict__ q, const unsigned short* __restrict__ k,
    const unsigned short* __restrict__ v, const unsigned short* __restrict__ c,
    const float* __restrict__ cn, unsigned short* __restrict__ ctxO)
{
  const int l0 = blockIdx.x * 32;
  const int h  = blockIdx.y;
  const int b  = blockIdx.z;
  const int tid = threadIdx.x;
  const int bh = b*NH + h;
  const size_t base = (size_t)(b*SS)*FF + h*DH;   // + row*FF + d

  __shared__ float Qs [32][68];
  __shared__ float Cls[32][68];
  __shared__ float Ks [64][68];
  __shared__ float Cs [64][68];   // C-tile for scores, then V-tile for PV
  __shared__ float P1 [32][68];
  __shared__ float P2 [32][68];
  __shared__ float cnl[32], cnr[64];
  __shared__ float m1s[32], s1s[32], sc1[32];
  __shared__ float m2s[32], s2s[32], sc2[32];

  // stage Q and C_l tiles (32 rows x 64), bf16 -> fp32
  {
    int row = tid >> 3, j0 = tid & 7;
    const unsigned short* qg = q + base + (size_t)(l0+row)*FF + j0*8;
    const unsigned short* cg = c + base + (size_t)(l0+row)*FF + j0*8;
    uint4 tq = *(const uint4*)qg;
    uint4 tc = *(const uint4*)cg;
    float* Qd = &Qs [row][j0*8];
    float* Cd = &Cls[row][j0*8];
    Qd[0]=__uint_as_float(tq.x<<16); Qd[1]=__uint_as_float(tq.x&0xFFFF0000u);
    Qd[2]=__uint_as_float(tq.y<<16); Qd[3]=__uint_as_float(tq.y&0xFFFF0000u);
    Qd[4]=__uint_as_float(tq.z<<16); Qd[5]=__uint_as_float(tq.z&0xFFFF0000u);
    Qd[6]=__uint_as_float(tq.w<<16); Qd[7]=__uint_as_float(tq.w&0xFFFF0000u);
    Cd[0]=__uint_as_float(tc.x<<16); Cd[1]=__uint_as_float(tc.x&0xFFFF0000u);
    Cd[2]=__uint_as_float(tc.y<<16); Cd[3]=__uint_as_float(tc.y&0xFFFF0000u);
    Cd[4]=__uint_as_float(tc.z<<16); Cd[5]=__uint_as_float(tc.z&0xFFFF0000u);
    Cd[6]=__uint_as_float(tc.w<<16); Cd[7]=__uint_as_float(tc.w&0xFFFF0000u);
  }
  if (tid < 32) {
    cnl[tid] = cn[(size_t)bh*SS + l0 + tid];
    m1s[tid] = -1e30f; s1s[tid] = 0.f;
    m2s[tid] = -1e30f; s2s[tid] = 0.f;
  }
  __syncthreads();

  const int ty = tid >> 4, tx = tid & 15;   // scores: l=ty*2+i, r=tx+16j
  const int lpv = tid >> 3, dq = tid & 7;   // PV: (l, d-octet)
  float ctx1[8] = {0,0,0,0,0,0,0,0};
  float ctx2[8] = {0,0,0,0,0,0,0,0};

  for (int it = 0; it < 8; ++it) {
    const int r0 = it*64;
    // ---- stage K and C key-tiles (64 x 64) ----
    {
      int row = tid >> 2, cix = tid & 3;
      const unsigned short* kg = k + base + (size_t)(r0+row)*FF + cix*16;
      const unsigned short* cg = c + base + (size_t)(r0+row)*FF + cix*16;
#pragma unroll
      for (int half = 0; half < 2; ++half) {
        uint4 tk = *(const uint4*)(kg + half*8);
        uint4 tc = *(const uint4*)(cg + half*8);
        float* Kd = &Ks[row][cix*16 + half*8];
        float* Cd = &Cs[row][cix*16 + half*8];
        Kd[0]=__uint_as_float(tk.x<<16); Kd[1]=__uint_as_float(tk.x&0xFFFF0000u);
        Kd[2]=__uint_as_float(tk.y<<16); Kd[3]=__uint_as_float(tk.y&0xFFFF0000u);
        Kd[4]=__uint_as_float(tk.z<<16); Kd[5]=__uint_as_float(tk.z&0xFFFF0000u);
        Kd[6]=__uint_as_float(tk.w<<16); Kd[7]=__uint_as_float(tk.w&0xFFFF0000u);
        Cd[0]=__uint_as_float(tc.x<<16); Cd[1]=__uint_as_float(tc.x&0xFFFF0000u);
        Cd[2]=__uint_as_float(tc.y<<16); Cd[3]=__uint_as_float(tc.y&0xFFFF0000u);
        Cd[4]=__uint_as_float(tc.z<<16); Cd[5]=__uint_as_float(tc.z&0xFFFF0000u);
        Cd[6]=__uint_as_float(tc.w<<16); Cd[7]=__uint_as_float(tc.w&0xFFFF0000u);
      }
      if (tid < 64) cnr[tid] = cn[(size_t)bh*SS + r0 + tid];
    }
    __syncthreads();

    // ---- dual scores, register tile 2l x 4r ----
    float qk[2][4] = {}, cc[2][4] = {};
#pragma unroll
    for (int d4 = 0; d4 < 16; ++d4) {
      const float4 q0 = *(const float4*)&Qs [ty*2  ][d4*4];
      const float4 q1 = *(const float4*)&Qs [ty*2+1][d4*4];
      const float4 a0 = *(const float4*)&Cls[ty*2  ][d4*4];
      const float4 a1 = *(const float4*)&Cls[ty*2+1][d4*4];
#pragma unroll
      for (int j = 0; j < 4; ++j) {
        const float4 k4 = *(const float4*)&Ks[tx + 16*j][d4*4];
        const float4 c4 = *(const float4*)&Cs[tx + 16*j][d4*4];
        qk[0][j] = fmaf(q0.x,k4.x, fmaf(q0.y,k4.y, fmaf(q0.z,k4.z, fmaf(q0.w,k4.w, qk[0][j]))));
        qk[1][j] = fmaf(q1.x,k4.x, fmaf(q1.y,k4.y, fmaf(q1.z,k4.z, fmaf(q1.w,k4.w, qk[1][j]))));
        cc[0][j] = fmaf(a0.x,c4.x, fmaf(a0.y,c4.y, fmaf(a0.z,c4.z, fmaf(a0.w,c4.w, cc[0][j]))));
        cc[1][j] = fmaf(a1.x,c4.x, fmaf(a1.y,c4.y, fmaf(a1.z,c4.z, fmaf(a1.w,c4.w, cc[1][j]))));
      }
    }

    // ---- online-softmax stats + exp tiles ----
#pragma unroll
    for (int i = 0; i < 2; ++i) {
      const int l  = ty*2 + i;
      const int lg = l0 + l;
      const float cni = cnl[l];
      float s1[4], s2[4];
#pragma unroll
      for (int j = 0; j < 4; ++j) {
        const int rl = tx + 16*j;
        s2[j] = qk[i][j] * 0.125f;
        s1[j] = 1.0f - cc[i][j]/(cni*cnr[rl]) + ((lg == r0+rl) ? 1.0f : 0.0f);
      }
      float t1 = fmaxf(fmaxf(s1[0],s1[1]), fmaxf(s1[2],s1[3]));
      float t2 = fmaxf(fmaxf(s2[0],s2[1]), fmaxf(s2[2],s2[3]));
#pragma unroll
      for (int off = 1; off < 16; off <<= 1) {
        t1 = fmaxf(t1, __shfl_xor(t1, off, 64));
        t2 = fmaxf(t2, __shfl_xor(t2, off, 64));
      }
      const float mo1 = m1s[l], mo2 = m2s[l];
      const float mn1 = fmaxf(mo1, t1), mn2 = fmaxf(mo2, t2);
      float e1sum = 0.f, e2sum = 0.f;
#pragma unroll
      for (int j = 0; j < 4; ++j) {
        const float e1 = __expf(s1[j] - mn1);
        const float e2 = __expf(s2[j] - mn2);
        P1[l][tx + 16*j] = e1;  e1sum += e1;
        P2[l][tx + 16*j] = e2;  e2sum += e2;
      }
#pragma unroll
      for (int off = 1; off < 16; off <<= 1) {
        e1sum += __shfl_xor(e1sum, off, 64);
        e2sum += __shfl_xor(e2sum, off, 64);
      }
      if (tx == 0) {
        const float f1 = __expf(mo1 - mn1);
        const float f2 = __expf(mo2 - mn2);
        s1s[l] = s1s[l]*f1 + e1sum;  m1s[l] = mn1;  sc1[l] = f1;
        s2s[l] = s2s[l]*f2 + e2sum;  m2s[l] = mn2;  sc2[l] = f2;
      }
    }
    __syncthreads();   // P1/P2, sc*, stats visible; scores done with Cs

    // ---- stage V tile into Cs ----
    {
      int row = tid >> 2, cix = tid & 3;
      const unsigned short* vg = v + base + (size_t)(r0+row)*FF + cix*16;
#pragma unroll
      for (int half = 0; half < 2; ++half) {
        uint4 tv = *(const uint4*)(vg + half*8);
        float* Vd = &Cs[row][cix*16 + half*8];
        Vd[0]=__uint_as_float(tv.x<<16); Vd[1]=__uint_as_float(tv.x&0xFFFF0000u);
        Vd[2]=__uint_as_float(tv.y<<16); Vd[3]=__uint_as_float(tv.y&0xFFFF0000u);
        Vd[4]=__uint_as_float(tv.z<<16); Vd[5]=__uint_as_float(tv.z&0xFFFF0000u);
        Vd[6]=__uint_as_float(tv.w<<16); Vd[7]=__uint_as_float(tv.w&0xFFFF0000u);
      }
    }
    __syncthreads();

    // ---- PV accumulate with rescale ----
    {
      const float f1 = sc1[lpv], f2 = sc2[lpv];
#pragma unroll
      for (int z = 0; z < 8; ++z) { ctx1[z] *= f1; ctx2[z] *= f2; }
      for (int r4 = 0; r4 < 64; r4 += 4) {
        const float4 p1v = *(const float4*)&P1[lpv][r4];
        const float4 p2v = *(const float4*)&P2[lpv][r4];
#pragma unroll
        for (int rr = 0; rr < 4; ++rr) {
          const float w1 = ((const float*)&p1v)[rr];
          const float w2 = ((const float*)&p2v)[rr];
          const float4 va = *(const float4*)&Cs[r4+rr][dq*8];
          const float4 vb = *(const float4*)&Cs[r4+rr][dq*8+4];
          ctx1[0]=fmaf(w1,va.x,ctx1[0]); ctx1[1]=fmaf(w1,va.y,ctx1[1]);
          ctx1[2]=fmaf(w1,va.z,ctx1[2]); ctx1[3]=fmaf(w1,va.w,ctx1[3]);
          ctx1[4]=fmaf(w1,vb.x,ctx1[4]); ctx1[5]=fmaf(w1,vb.y,ctx1[5]);
          ctx1[6]=fmaf(w1,vb.z,ctx1[6]); ctx1[7]=fmaf(w1,vb.w,ctx1[7]);
          ctx2[0]=fmaf(w2,va.x,ctx2[0]); ctx2[1]=fmaf(w2,va.y,ctx2[1]);
          ctx2[2]=fmaf(w2,va.z,ctx2[2]); ctx2[3]=fmaf(w2,va.w,ctx2[3]);
          ctx2[4]=fmaf(w2,vb.x,ctx2[4]); ctx2[5]=fmaf(w2,vb.y,ctx2[5]);
          ctx2[6]=fmaf(w2,vb.z,ctx2[6]); ctx2[7]=fmaf(w2,vb.w,ctx2[7]);
        }
      }
    }
    __syncthreads();   // PV done before next tile overwrites Ks/Cs/P
  }

  // ---- final blend + bf16 store ([MM,DD] layout) ----
  const float inv1 = 0.5f / s1s[lpv];
  const float inv2 = 0.5f / s2s[lpv];
  float o[8];
#pragma unroll
  for (int z = 0; z < 8; ++z) o[z] = ctx1[z]*inv1 + ctx2[z]*inv2;
  unsigned short* og = ctxO + (size_t)(b*SS + l0+lpv)*DD + h*DH + dq*8;
  uint4 u;
  u.x = (unsigned)f2bf(o[0]) | ((unsigned)f2bf(o[1]) << 16);
  u.y = (unsigned)f2bf(o[2]) | ((unsigned)f2bf(o[3]) << 16);
  u.z = (unsigned)f2bf(o[4]) | ((unsigned)f2bf(o[5]) << 16);
  u.w = (unsigned)f2bf(o[6]) | ((unsigned)f2bf(o[7]) << 16);
  *(uint4*)og = u;
}

// ---------------- in-place row LayerNorm over D=768, + bf16 mirror ----------------
__global__ __launch_bounds__(256) void ln_k(float* __restrict__ x,
                                            const float* __restrict__ g,
                                            const float* __restrict__ b,
                                            unsigned short* __restrict__ xb) {
  __shared__ float xs[DD];
  __shared__ float red[4];
  const int tid = threadIdx.x;
  float* xr = x + (size_t)blockIdx.x * DD;
  unsigned short* xbr = xb + (size_t)blockIdx.x * DD;
  float s = 0.f;
  for (int d = tid; d < DD; d += 256) { float v = xr[d]; xs[d] = v; s += v; }
#pragma unroll
  for (int off = 32; off; off >>= 1) s += __shfl_xor(s, off, 64);
  if ((tid & 63) == 0) red[tid >> 6] = s;
  __syncthreads();
  float mu = (red[0]+red[1]+red[2]+red[3]) * (1.f/DD);
  __syncthreads();
  float s2 = 0.f;
  for (int d = tid; d < DD; d += 256) { float t = xs[d]-mu; s2 += t*t; }
#pragma unroll
  for (int off = 32; off; off >>= 1) s2 += __shfl_xor(s2, off, 64);
  if ((tid & 63) == 0) red[tid >> 6] = s2;
  __syncthreads();
  float var = (red[0]+red[1]+red[2]+red[3]) * (1.f/DD);
  float rstd = rsqrtf(var + 1e-12f);
  for (int d = tid; d < DD; d += 256) {
    float o = (xs[d]-mu)*rstd*g[d] + b[d];
    xr[d] = o;
    xbr[d] = f2bf(o);
  }
}

// ---------------- launcher ----------------
extern "C" void kernel_launch(void* const* d_in, const int* in_sizes, int n_in,
                              void* d_out, int out_size, void* d_ws, size_t ws_size,
                              hipStream_t stream) {
  const float* hs  = (const float*)d_in[0];
  const float* Wq  = (const float*)d_in[1];  const float* bq  = (const float*)d_in[2];
  const float* Wk  = (const float*)d_in[3];  const float* bk  = (const float*)d_in[4];
  const float* Wv  = (const float*)d_in[5];  const float* bv  = (const float*)d_in[6];
  const float* Wc  = (const float*)d_in[7];  const float* bc  = (const float*)d_in[8];
  const float* Wo  = (const float*)d_in[9];  const float* bo  = (const float*)d_in[10];
  const float* g1  = (const float*)d_in[11]; const float* b1  = (const float*)d_in[12];
  const float* Wi  = (const float*)d_in[13]; const float* bi  = (const float*)d_in[14];
  const float* Wo2 = (const float*)d_in[15]; const float* bo2 = (const float*)d_in[16];
  const float* g2  = (const float*)d_in[17]; const float* b2  = (const float*)d_in[18];

  const size_t XN  = (size_t)MM * DD;       // 6,291,456
  const size_t HN  = (size_t)MM * FF;       // 25,165,824
  const int    nBH = BB*NH*SS;              // 98304
  const size_t WTN = 7667712;               // per-layer transposed weights (elems)

  char* p = (char*)d_ws;
  float*          x      = (float*)p;           p += XN*4;
  float*          attnf  = (float*)p;           p += XN*4;
  unsigned short* qkvc16 = (unsigned short*)p;  p += HN*2;   // also hb16 (aliased)
  unsigned short* xb16   = (unsigned short*)p;  p += XN*2;
  unsigned short* ctx16  = (unsigned short*)p;  p += XN*2;
  unsigned short* attn16 = (unsigned short*)p;  p += XN*2;
  unsigned short* WT     = (unsigned short*)p;  p += WTN*2;
  float*          bqkvc  = (float*)p;           p += 3072*4;
  float*          cnb    = (float*)p;           p += (size_t)nBH*4;
  const size_t need = (size_t)(p - (char*)d_ws);
  if (ws_size < need) return;

  unsigned short* WqkvcT = WT;                    // [3072][768]
  unsigned short* WoT    = WT + 2359296;          // [768][768]
  unsigned short* WiT    = WT + 2949120;          // [3072][768]
  unsigned short* Wo2T   = WT + 5308416;          // [768][3072]
  unsigned short* hb16   = qkvc16;                // FFN intermediate aliases QKVC

  cvt_dual_k<<<4096, 256, 0, stream>>>(hs, x, xb16, (int)XN);

  dim3 gGQ(FF/128, MM/128);   // 24 x 64  (QKVC, Wi)
  dim3 gGD(DD/128, MM/128);   // 6  x 64  (Wo, Wo2)
  dim3 gA(SS/32, NH, BB);     // 16 x 12 x 16
  dim3 tDD(DD/32, DD/32);     // 24 x 24
  dim3 tDF(FF/32, DD/32);     // 96 x 24  (src [D,F])
  dim3 tFD(DD/32, FF/32);     // 24 x 96  (src [F,D])

  for (int i = 0; i < NL; ++i) {
    const size_t wD = (size_t)i*DD*DD, wF = (size_t)i*DD*FF;
    // per-layer weight transpose-convert (fp32 [K,N] -> bf16 [N,K])
    tcvt_k<<<tDD, 256, 0, stream>>>(Wq + wD, WqkvcT,            DD, DD);
    tcvt_k<<<tDD, 256, 0, stream>>>(Wk + wD, WqkvcT +  768*768, DD, DD);
    tcvt_k<<<tDD, 256, 0, stream>>>(Wv + wD, WqkvcT + 1536*768, DD, DD);
    tcvt_k<<<tDD, 256, 0, stream>>>(Wc + wD, WqkvcT + 2304*768, DD, DD);
    tcvt_k<<<tDD, 256, 0, stream>>>(Wo + wD, WoT,  DD, DD);
    tcvt_k<<<tDF, 256, 0, stream>>>(Wi + wF, WiT,  DD, FF);
    tcvt_k<<<tFD, 256, 0, stream>>>(Wo2 + wF, Wo2T, FF, DD);
    bcat_k<<<12, 256, 0, stream>>>(bq + (size_t)i*DD, bk + (size_t)i*DD,
                                   bv + (size_t)i*DD, bc + (size_t)i*DD, bqkvc);

    // fused QKVC projection: [8192,768] @ [768,3072] -> bf16 [8192,3072]
    mgemm_k<0,1><<<gGQ, 256, 0, stream>>>(xb16, WqkvcT, bqkvc, nullptr, qkvc16, MM, FF, DD);

    cnorm_k<<<nBH, 64, 0, stream>>>(qkvc16 + 2304, cnb);
    attn2_k<<<gA, 256, 0, stream>>>(qkvc16, qkvc16 + 768, qkvc16 + 1536, qkvc16 + 2304,
                                    cnb, ctx16);

    // attn_out = LN1(ctx @ Wo + bo + x)
    mgemm_k<1,0><<<gGD, 256, 0, stream>>>(ctx16, WoT, bo + (size_t)i*DD, x, attnf, MM, DD, DD);
    ln_k<<<MM, 256, 0, stream>>>(attnf, g1 + (size_t)i*DD, b1 + (size_t)i*DD, attn16);

    // h = gelu(attn @ Wi + bi) -> bf16 (overwrites dead qkvc16)
    mgemm_k<2,1><<<gGQ, 256, 0, stream>>>(attn16, WiT, bi + (size_t)i*FF, nullptr, hb16, MM, FF, DD);
    // x = LN2(h @ Wo2 + bo2 + attn)
    mgemm_k<1,0><<<gGD, 256, 0, stream>>>(hb16, Wo2T, bo2 + (size_t)i*DD, attnf, x, MM, DD, FF);
    ln_k<<<MM, 256, 0, stream>>>(x, g2 + (size_t)i*DD, b2 + (size_t)i*DD, xb16);
  }

  copy_f32_k<<<4096, 256, 0, stream>>>(x, (float*)d_out, (int)XN);
}

// Round 7
// 1924.914 us; speedup vs baseline: 18.9857x; 7.0320x over previous
//
#include <hip/hip_runtime.h>
#include <math.h>

#define DD 768
#define FF 3072
#define SS 512
#define BB 16
#define NH 12
#define DH 64
#define NL 4
#define MM (BB*SS)   // 8192

typedef __attribute__((ext_vector_type(8))) short short8;
typedef __attribute__((ext_vector_type(4))) float f32x4;

__device__ __forceinline__ unsigned short f2bf(float f) {
  unsigned u = __float_as_uint(f);
  return (unsigned short)((u + 0x7FFFu + ((u >> 16) & 1u)) >> 16);
}
__device__ __forceinline__ float bf2f(unsigned short s) {
  return __uint_as_float(((unsigned)s) << 16);
}

#define GLOAD_LDS(g, l) \
  __builtin_amdgcn_global_load_lds((const __attribute__((address_space(1))) void*)(g), \
                                   (__attribute__((address_space(3))) void*)(l), 16, 0, 0)

// ---------------- copy / convert ----------------
__global__ __launch_bounds__(256) void copy_f32_k(const float* __restrict__ in,
                                                  float* __restrict__ out, int n) {
  for (int i = blockIdx.x*256 + threadIdx.x; i < n; i += gridDim.x*256)
    out[i] = in[i];
}
__global__ __launch_bounds__(256) void cvt_dual_k(const float* __restrict__ in,
                                                  float* __restrict__ outf,
                                                  unsigned short* __restrict__ outb, int n) {
  for (int i = blockIdx.x*256 + threadIdx.x; i < n; i += gridDim.x*256) {
    float v = in[i]; outf[i] = v; outb[i] = f2bf(v);
  }
}

// fp32 [K,N] -> bf16 [N,K] tiled transpose-convert
__global__ __launch_bounds__(256) void tcvt_k(const float* __restrict__ src,
                                              unsigned short* __restrict__ dst,
                                              int K, int N) {
  __shared__ float t[32][33];
  const int n0 = blockIdx.x*32, k0 = blockIdx.y*32;
  const int tx = threadIdx.x & 31, ty = threadIdx.x >> 5;
#pragma unroll
  for (int i = 0; i < 32; i += 8)
    t[ty+i][tx] = src[(size_t)(k0+ty+i)*N + n0+tx];
  __syncthreads();
#pragma unroll
  for (int i = 0; i < 32; i += 8)
    dst[(size_t)(n0+ty+i)*K + k0+tx] = f2bf(t[tx][ty+i]);
}

// concat 4x768 biases -> 3072
__global__ __launch_bounds__(256) void bcat_k(const float* __restrict__ a,
                                              const float* __restrict__ b,
                                              const float* __restrict__ c,
                                              const float* __restrict__ d,
                                              float* __restrict__ out) {
  int i = blockIdx.x*256 + threadIdx.x;   // 0..3071
  int w = i / 768;
  const float* s = (w == 0) ? a : (w == 1) ? b : (w == 2) ? c : d;
  out[i] = s[i - w*768];
}

// ---------------- MFMA bf16 GEMM: C[M,N] = A[M,K] @ Bw[N,K]^T + bias ----------------
// EPI: 0 bias; 1 bias+resid(fp32); 2 bias+exact gelu.  OBF: 1 -> bf16 out, 0 -> fp32 out.
template<int EPI, int OBF>
__global__ __launch_bounds__(256) void mgemm_k(
    const unsigned short* __restrict__ A,   // [M,K] bf16
    const unsigned short* __restrict__ Bw,  // [N,K] bf16 (pre-transposed weights)
    const float* __restrict__ bias,         // [N] fp32
    const float* __restrict__ resid,        // [M,N] fp32 (EPI==1)
    void* __restrict__ Cout, int M, int N, int K)
{
  __shared__ __align__(16) unsigned short As[128*32];
  __shared__ __align__(16) unsigned short Bs[128*32];
  const int bm = blockIdx.y*128, bn = blockIdx.x*128;
  const int tid = threadIdx.x;
  const int wave = tid >> 6, lane = tid & 63;
  const int wm = (wave >> 1)*64, wn = (wave & 1)*64;

  f32x4 acc[4][4] = {};

  const unsigned short* Ag = A  + (size_t)(bm + wave*32 + (lane>>2))*K + (lane&3)*8;
  const unsigned short* Bg = Bw + (size_t)(bn + wave*32 + (lane>>2))*K + (lane&3)*8;
  unsigned short* AsW = As + wave*32*32;
  unsigned short* BsW = Bs + wave*32*32;

  for (int k0 = 0; k0 < K; k0 += 32) {
    GLOAD_LDS(Ag,                AsW);
    GLOAD_LDS(Ag + 16*(size_t)K, AsW + 16*32);
    GLOAD_LDS(Bg,                BsW);
    GLOAD_LDS(Bg + 16*(size_t)K, BsW + 16*32);
    Ag += 32; Bg += 32;
    __syncthreads();
    short8 af[4], bfr[4];
#pragma unroll
    for (int i = 0; i < 4; ++i) {
      af[i]  = *(const short8*)&As[(wm + i*16 + (lane & 15))*32 + (lane >> 4)*8];
      bfr[i] = *(const short8*)&Bs[(wn + i*16 + (lane & 15))*32 + (lane >> 4)*8];
    }
#pragma unroll
    for (int i = 0; i < 4; ++i)
#pragma unroll
      for (int j = 0; j < 4; ++j)
        acc[i][j] = __builtin_amdgcn_mfma_f32_16x16x32_bf16(af[i], bfr[j], acc[i][j], 0, 0, 0);
    __syncthreads();
  }

  const int col0 = bn + wn + (lane & 15);
  const int row0 = bm + wm + (lane >> 4)*4;
#pragma unroll
  for (int i = 0; i < 4; ++i) {
#pragma unroll
    for (int j = 0; j < 4; ++j) {
      const int n = col0 + j*16;
      const float bv = bias[n];
#pragma unroll
      for (int r = 0; r < 4; ++r) {
        const int m = row0 + i*16 + r;
        float v = acc[i][j][r] + bv;
        if (EPI == 1) v += resid[(size_t)m*N + n];
        if (EPI == 2) v = 0.5f*v*(1.0f + erff(v*0.70710678118654752f));
        if (OBF) ((unsigned short*)Cout)[(size_t)m*N + n] = f2bf(v);
        else     ((float*)Cout)[(size_t)m*N + n] = v;
      }
    }
  }
}

// ---------------- per-(b,h,s) context-vector L2 norm (bf16 in, pitch FF) ----------------
__global__ __launch_bounds__(64) void cnorm_k(const unsigned short* __restrict__ c,
                                              float* __restrict__ cn) {
  int idx = blockIdx.x;          // (b*NH + h)*SS + s
  int s  = idx % SS;
  int bh = idx / SS;
  int h  = bh % NH;
  int b  = bh / NH;
  int tid = threadIdx.x;
  float v = bf2f(c[((size_t)(b*SS + s))*FF + h*DH + tid]);
  float ss = v*v;
#pragma unroll
  for (int off = 32; off; off >>= 1) ss += __shfl_xor(ss, off, 64);
  if (tid == 0) cn[idx] = sqrtf(ss);
}

// ---------------- MFMA flash-style dual-branch attention ----------------
// Block: (64 q-rows, head h, batch b), 256 threads = 4 waves; wave w owns q-rows
// [wm, wm+16). Streams 8 key-tiles of 64. Scores via mfma_f32_16x16x32_bf16
// (QK^T and CC^T), online softmax for both branches with register-resident
// per-row stats, exp-tiles -> bf16 P in LDS -> A-frags, PV via MFMA vs V^T.
__global__ __launch_bounds__(256) void attn3_k(
    const unsigned short* __restrict__ q, const unsigned short* __restrict__ k,
    const unsigned short* __restrict__ v, const unsigned short* __restrict__ c,
    const float* __restrict__ cn, unsigned short* __restrict__ ctxO)
{
  const int l0 = blockIdx.x * 64;
  const int h  = blockIdx.y;
  const int b  = blockIdx.z;
  const int tid = threadIdx.x;
  const int wave = tid >> 6, lane = tid & 63;
  const int wm = wave * 16;
  const int fr = lane & 15;          // frag row (A/B) / col (C,D)
  const int fg = lane >> 4;          // k-group (A/B) / row-quad (C,D)
  const int bh = b*NH + h;
  const size_t base = (size_t)(b*SS)*FF + h*DH;

  // pitch 72 halfwords = 144 B (multiple of 16 -> aligned b128; 2-way-conflict reads)
  __shared__ unsigned short Qs[64*72], Cls[64*72], Ks[64*72], Crs[64*72],
                            VT[64*72], P1s[64*72], P2s[64*72];
  __shared__ float cnl[64], cnr[64];

  // ---- stage Q, C_l (64 rows x 64 halfwords each) ----
  {
    const int row = tid >> 2, seg = tid & 3;
    const unsigned short* qg = q + base + (size_t)(l0+row)*FF;
    const unsigned short* cg = c + base + (size_t)(l0+row)*FF;
    *(uint4*)&Qs [row*72 + seg*8]     = *(const uint4*)(qg + seg*8);
    *(uint4*)&Qs [row*72 + (seg+4)*8] = *(const uint4*)(qg + (seg+4)*8);
    *(uint4*)&Cls[row*72 + seg*8]     = *(const uint4*)(cg + seg*8);
    *(uint4*)&Cls[row*72 + (seg+4)*8] = *(const uint4*)(cg + (seg+4)*8);
  }
  if (tid < 64) cnl[tid] = cn[(size_t)bh*SS + l0 + tid];
  __syncthreads();

  // loop-invariant A-frags (Q, C_l rows of this wave)
  const short8 aQ0 = *(const short8*)&Qs [(wm+fr)*72 + fg*8];
  const short8 aQ1 = *(const short8*)&Qs [(wm+fr)*72 + fg*8 + 32];
  const short8 aC0 = *(const short8*)&Cls[(wm+fr)*72 + fg*8];
  const short8 aC1 = *(const short8*)&Cls[(wm+fr)*72 + fg*8 + 32];

  float rm1[4], rs1[4], rm2[4], rs2[4];
#pragma unroll
  for (int r = 0; r < 4; ++r) { rm1[r] = -1e30f; rs1[r] = 0.f; rm2[r] = -1e30f; rs2[r] = 0.f; }
  f32x4 oc1[4] = {}, oc2[4] = {};

  for (int it = 0; it < 8; ++it) {
    const int r0 = it*64;
    // ---- stage K, C_r, V^T ----
    {
      const int row = tid >> 2, seg = tid & 3;
      const unsigned short* kg = k + base + (size_t)(r0+row)*FF;
      const unsigned short* cg = c + base + (size_t)(r0+row)*FF;
      const unsigned short* vg = v + base + (size_t)(r0+row)*FF;
      uint4 ka = *(const uint4*)(kg + seg*8);
      uint4 kb = *(const uint4*)(kg + (seg+4)*8);
      uint4 ca = *(const uint4*)(cg + seg*8);
      uint4 cb = *(const uint4*)(cg + (seg+4)*8);
      uint4 va = *(const uint4*)(vg + seg*8);
      uint4 vb = *(const uint4*)(vg + (seg+4)*8);
      *(uint4*)&Ks [row*72 + seg*8]     = ka;
      *(uint4*)&Ks [row*72 + (seg+4)*8] = kb;
      *(uint4*)&Crs[row*72 + seg*8]     = ca;
      *(uint4*)&Crs[row*72 + (seg+4)*8] = cb;
      const unsigned short* pa = (const unsigned short*)&va;
      const unsigned short* pb = (const unsigned short*)&vb;
#pragma unroll
      for (int u = 0; u < 8; ++u) {
        VT[(seg*8+u)*72 + row]     = pa[u];
        VT[((seg+4)*8+u)*72 + row] = pb[u];
      }
      if (tid < 64) cnr[tid] = cn[(size_t)bh*SS + r0 + tid];
    }
    __syncthreads();

    // ---- dual scores via MFMA: wave computes 16 q-rows x 64 keys ----
    f32x4 s1a[4] = {}, s2a[4] = {};
#pragma unroll
    for (int nt = 0; nt < 4; ++nt) {
      short8 bK0 = *(const short8*)&Ks [(nt*16+fr)*72 + fg*8];
      short8 bK1 = *(const short8*)&Ks [(nt*16+fr)*72 + fg*8 + 32];
      short8 bC0 = *(const short8*)&Crs[(nt*16+fr)*72 + fg*8];
      short8 bC1 = *(const short8*)&Crs[(nt*16+fr)*72 + fg*8 + 32];
      s2a[nt] = __builtin_amdgcn_mfma_f32_16x16x32_bf16(aQ0, bK0, s2a[nt], 0,0,0);
      s2a[nt] = __builtin_amdgcn_mfma_f32_16x16x32_bf16(aQ1, bK1, s2a[nt], 0,0,0);
      s1a[nt] = __builtin_amdgcn_mfma_f32_16x16x32_bf16(aC0, bC0, s1a[nt], 0,0,0);
      s1a[nt] = __builtin_amdgcn_mfma_f32_16x16x32_bf16(aC1, bC1, s1a[nt], 0,0,0);
    }

    // ---- branch scores; D-layout: row = wm + fg*4 + reg, col = nt*16 + fr ----
    float sv1[4][4], sv2[4][4];   // [reg][nt]
#pragma unroll
    for (int nt = 0; nt < 4; ++nt) {
#pragma unroll
      for (int reg = 0; reg < 4; ++reg) {
        const int ql = wm + fg*4 + reg;
        const int rr = nt*16 + fr;
        sv2[reg][nt] = s2a[nt][reg] * 0.125f;
        sv1[reg][nt] = 1.0f - s1a[nt][reg]/(cnl[ql]*cnr[rr])
                     + ((l0+ql) == (r0+rr) ? 1.0f : 0.0f);
      }
    }

    // ---- online softmax update (per row; stats replicated across 16 lanes) ----
#pragma unroll
    for (int reg = 0; reg < 4; ++reg) {
      const int ql = wm + fg*4 + reg;
      float t1 = fmaxf(fmaxf(sv1[reg][0],sv1[reg][1]), fmaxf(sv1[reg][2],sv1[reg][3]));
      float t2 = fmaxf(fmaxf(sv2[reg][0],sv2[reg][1]), fmaxf(sv2[reg][2],sv2[reg][3]));
#pragma unroll
      for (int off = 1; off < 16; off <<= 1) {
        t1 = fmaxf(t1, __shfl_xor(t1, off, 64));
        t2 = fmaxf(t2, __shfl_xor(t2, off, 64));
      }
      const float mn1 = fmaxf(rm1[reg], t1), mn2 = fmaxf(rm2[reg], t2);
      const float f1 = __expf(rm1[reg] - mn1), f2 = __expf(rm2[reg] - mn2);
      float e1 = 0.f, e2 = 0.f;
#pragma unroll
      for (int nt = 0; nt < 4; ++nt) {
        const float x1 = __expf(sv1[reg][nt] - mn1);
        const float x2 = __expf(sv2[reg][nt] - mn2);
        P1s[ql*72 + nt*16 + fr] = f2bf(x1);
        P2s[ql*72 + nt*16 + fr] = f2bf(x2);
        e1 += x1; e2 += x2;
      }
#pragma unroll
      for (int off = 1; off < 16; off <<= 1) {
        e1 += __shfl_xor(e1, off, 64);
        e2 += __shfl_xor(e2, off, 64);
      }
      rs1[reg] = rs1[reg]*f1 + e1;  rm1[reg] = mn1;
      rs2[reg] = rs2[reg]*f2 + e2;  rm2[reg] = mn2;
#pragma unroll
      for (int nt = 0; nt < 4; ++nt) { oc1[nt][reg] *= f1; oc2[nt][reg] *= f2; }
    }
    __syncthreads();   // P tiles + V^T visible to all waves

    // ---- PV via MFMA: A = P rows (wave's 16 q-rows), B = V^T ----
    short8 p10 = *(const short8*)&P1s[(wm+fr)*72 + fg*8];
    short8 p11 = *(const short8*)&P1s[(wm+fr)*72 + fg*8 + 32];
    short8 p20 = *(const short8*)&P2s[(wm+fr)*72 + fg*8];
    short8 p21 = *(const short8*)&P2s[(wm+fr)*72 + fg*8 + 32];
#pragma unroll
    for (int nt = 0; nt < 4; ++nt) {
      short8 bv0 = *(const short8*)&VT[(nt*16+fr)*72 + fg*8];
      short8 bv1 = *(const short8*)&VT[(nt*16+fr)*72 + fg*8 + 32];
      oc1[nt] = __builtin_amdgcn_mfma_f32_16x16x32_bf16(p10, bv0, oc1[nt], 0,0,0);
      oc1[nt] = __builtin_amdgcn_mfma_f32_16x16x32_bf16(p11, bv1, oc1[nt], 0,0,0);
      oc2[nt] = __builtin_amdgcn_mfma_f32_16x16x32_bf16(p20, bv0, oc2[nt], 0,0,0);
      oc2[nt] = __builtin_amdgcn_mfma_f32_16x16x32_bf16(p21, bv1, oc2[nt], 0,0,0);
    }
    __syncthreads();   // PV done before next staging overwrites Ks/Crs/VT
  }

  // ---- final blend + bf16 store; D-layout row = wm+fg*4+reg, col d = nt*16+fr ----
#pragma unroll
  for (int reg = 0; reg < 4; ++reg) {
    const float i1 = 0.5f / rs1[reg];
    const float i2 = 0.5f / rs2[reg];
    const int Mrow = b*SS + l0 + wm + fg*4 + reg;
    unsigned short* og = ctxO + (size_t)Mrow*DD + h*DH;
#pragma unroll
    for (int nt = 0; nt < 4; ++nt)
      og[nt*16 + fr] = f2bf(oc1[nt][reg]*i1 + oc2[nt][reg]*i2);
  }
}

// ---------------- in-place row LayerNorm over D=768, + bf16 mirror ----------------
__global__ __launch_bounds__(256) void ln_k(float* __restrict__ x,
                                            const float* __restrict__ g,
                                            const float* __restrict__ b,
                                            unsigned short* __restrict__ xb) {
  __shared__ float xs[DD];
  __shared__ float red[4];
  const int tid = threadIdx.x;
  float* xr = x + (size_t)blockIdx.x * DD;
  unsigned short* xbr = xb + (size_t)blockIdx.x * DD;
  float s = 0.f;
  for (int d = tid; d < DD; d += 256) { float v = xr[d]; xs[d] = v; s += v; }
#pragma unroll
  for (int off = 32; off; off >>= 1) s += __shfl_xor(s, off, 64);
  if ((tid & 63) == 0) red[tid >> 6] = s;
  __syncthreads();
  float mu = (red[0]+red[1]+red[2]+red[3]) * (1.f/DD);
  __syncthreads();
  float s2 = 0.f;
  for (int d = tid; d < DD; d += 256) { float t = xs[d]-mu; s2 += t*t; }
#pragma unroll
  for (int off = 32; off; off >>= 1) s2 += __shfl_xor(s2, off, 64);
  if ((tid & 63) == 0) red[tid >> 6] = s2;
  __syncthreads();
  float var = (red[0]+red[1]+red[2]+red[3]) * (1.f/DD);
  float rstd = rsqrtf(var + 1e-12f);
  for (int d = tid; d < DD; d += 256) {
    float o = (xs[d]-mu)*rstd*g[d] + b[d];
    xr[d] = o;
    xbr[d] = f2bf(o);
  }
}

// ---------------- launcher ----------------
extern "C" void kernel_launch(void* const* d_in, const int* in_sizes, int n_in,
                              void* d_out, int out_size, void* d_ws, size_t ws_size,
                              hipStream_t stream) {
  const float* hs  = (const float*)d_in[0];
  const float* Wq  = (const float*)d_in[1];  const float* bq  = (const float*)d_in[2];
  const float* Wk  = (const float*)d_in[3];  const float* bk  = (const float*)d_in[4];
  const float* Wv  = (const float*)d_in[5];  const float* bv  = (const float*)d_in[6];
  const float* Wc  = (const float*)d_in[7];  const float* bc  = (const float*)d_in[8];
  const float* Wo  = (const float*)d_in[9];  const float* bo  = (const float*)d_in[10];
  const float* g1  = (const float*)d_in[11]; const float* b1  = (const float*)d_in[12];
  const float* Wi  = (const float*)d_in[13]; const float* bi  = (const float*)d_in[14];
  const float* Wo2 = (const float*)d_in[15]; const float* bo2 = (const float*)d_in[16];
  const float* g2  = (const float*)d_in[17]; const float* b2  = (const float*)d_in[18];

  const size_t XN  = (size_t)MM * DD;       // 6,291,456
  const size_t HN  = (size_t)MM * FF;       // 25,165,824
  const int    nBH = BB*NH*SS;              // 98304
  const size_t WTN = 7667712;               // per-layer transposed weights (elems)

  char* p = (char*)d_ws;
  float*          x      = (float*)p;           p += XN*4;
  float*          attnf  = (float*)p;           p += XN*4;
  unsigned short* qkvc16 = (unsigned short*)p;  p += HN*2;   // also hb16 (aliased)
  unsigned short* xb16   = (unsigned short*)p;  p += XN*2;
  unsigned short* ctx16  = (unsigned short*)p;  p += XN*2;
  unsigned short* attn16 = (unsigned short*)p;  p += XN*2;
  unsigned short* WT     = (unsigned short*)p;  p += WTN*2;
  float*          bqkvc  = (float*)p;           p += 3072*4;
  float*          cnb    = (float*)p;           p += (size_t)nBH*4;
  const size_t need = (size_t)(p - (char*)d_ws);
  if (ws_size < need) return;

  unsigned short* WqkvcT = WT;                    // [3072][768]
  unsigned short* WoT    = WT + 2359296;          // [768][768]
  unsigned short* WiT    = WT + 2949120;          // [3072][768]
  unsigned short* Wo2T   = WT + 5308416;          // [768][3072]
  unsigned short* hb16   = qkvc16;                // FFN intermediate aliases QKVC

  cvt_dual_k<<<4096, 256, 0, stream>>>(hs, x, xb16, (int)XN);

  dim3 gGQ(FF/128, MM/128);   // 24 x 64  (QKVC, Wi)
  dim3 gGD(DD/128, MM/128);   // 6  x 64  (Wo, Wo2)
  dim3 gA(SS/64, NH, BB);     // 8 x 12 x 16 = 1536
  dim3 tDD(DD/32, DD/32);     // 24 x 24
  dim3 tDF(FF/32, DD/32);     // 96 x 24  (src [D,F])
  dim3 tFD(DD/32, FF/32);     // 24 x 96  (src [F,D])

  for (int i = 0; i < NL; ++i) {
    const size_t wD = (size_t)i*DD*DD, wF = (size_t)i*DD*FF;
    // per-layer weight transpose-convert (fp32 [K,N] -> bf16 [N,K])
    tcvt_k<<<tDD, 256, 0, stream>>>(Wq + wD, WqkvcT,            DD, DD);
    tcvt_k<<<tDD, 256, 0, stream>>>(Wk + wD, WqkvcT +  768*768, DD, DD);
    tcvt_k<<<tDD, 256, 0, stream>>>(Wv + wD, WqkvcT + 1536*768, DD, DD);
    tcvt_k<<<tDD, 256, 0, stream>>>(Wc + wD, WqkvcT + 2304*768, DD, DD);
    tcvt_k<<<tDD, 256, 0, stream>>>(Wo + wD, WoT,  DD, DD);
    tcvt_k<<<tDF, 256, 0, stream>>>(Wi + wF, WiT,  DD, FF);
    tcvt_k<<<tFD, 256, 0, stream>>>(Wo2 + wF, Wo2T, FF, DD);
    bcat_k<<<12, 256, 0, stream>>>(bq + (size_t)i*DD, bk + (size_t)i*DD,
                                   bv + (size_t)i*DD, bc + (size_t)i*DD, bqkvc);

    // fused QKVC projection: [8192,768] @ [768,3072] -> bf16 [8192,3072]
    mgemm_k<0,1><<<gGQ, 256, 0, stream>>>(xb16, WqkvcT, bqkvc, nullptr, qkvc16, MM, FF, DD);

    cnorm_k<<<nBH, 64, 0, stream>>>(qkvc16 + 2304, cnb);
    attn3_k<<<gA, 256, 0, stream>>>(qkvc16, qkvc16 + 768, qkvc16 + 1536, qkvc16 + 2304,
                                    cnb, ctx16);

    // attn_out = LN1(ctx @ Wo + bo + x)
    mgemm_k<1,0><<<gGD, 256, 0, stream>>>(ctx16, WoT, bo + (size_t)i*DD, x, attnf, MM, DD, DD);
    ln_k<<<MM, 256, 0, stream>>>(attnf, g1 + (size_t)i*DD, b1 + (size_t)i*DD, attn16);

    // h = gelu(attn @ Wi + bi) -> bf16 (overwrites dead qkvc16)
    mgemm_k<2,1><<<gGQ, 256, 0, stream>>>(attn16, WiT, bi + (size_t)i*FF, nullptr, hb16, MM, FF, DD);
    // x = LN2(h @ Wo2 + bo2 + attn)
    mgemm_k<1,0><<<gGD, 256, 0, stream>>>(hb16, Wo2T, bo2 + (size_t)i*DD, attnf, x, MM, DD, FF);
    ln_k<<<MM, 256, 0, stream>>>(x, g2 + (size_t)i*DD, b2 + (size_t)i*DD, xb16);
  }

  copy_f32_k<<<4096, 256, 0, stream>>>(x, (float*)d_out, (int)XN);
}